// Round 3
// baseline (1148.182 us; speedup 1.0000x reference)
//
#include <hip/hip_runtime.h>
#include <math.h>

#define QLEN 1024
#define BSZ 4
#define NH 10
#define DH 38
#define DM 380
#define DI 900
#define H3 1140          // 3*NH*DH
#define RLEN 2049
#define SCALE 0.16222142113076254f   // 1/sqrt(38)

// ---------------- generic tiled f32 GEMM:  C[M,N] = A[M,K] * B[N,K]^T ----------------
// EPI: 0 = none, 1 = +bias then relu, 2 = +bias
template<int EPI>
__global__ __launch_bounds__(256)
void gemm_abt(const float* __restrict__ A, const float* __restrict__ B,
              const float* __restrict__ bias, float* __restrict__ C,
              int M, int N, int K) {
    __shared__ float As[16][16];
    __shared__ float Bs[16][17];   // +1 pad: avoid 16-way bank conflict on Bs[tx][k]
    const int tx = threadIdx.x, ty = threadIdx.y;
    const int row = blockIdx.y * 16 + ty;
    const int col = blockIdx.x * 16 + tx;
    float acc = 0.f;
    const int ntk = (K + 15) / 16;
    for (int kt = 0; kt < ntk; ++kt) {
        const int k0 = kt * 16;
        As[ty][tx] = (row < M && (k0 + tx) < K) ? A[(size_t)row * K + k0 + tx] : 0.f;
        const int brow = blockIdx.x * 16 + ty;
        Bs[ty][tx] = (brow < N && (k0 + tx) < K) ? B[(size_t)brow * K + k0 + tx] : 0.f;
        __syncthreads();
        #pragma unroll
        for (int k = 0; k < 16; ++k) acc += As[ty][k] * Bs[tx][k];
        __syncthreads();
    }
    if (row < M && col < N) {
        if (EPI == 1) acc = fmaxf(acc + bias[col], 0.f);
        else if (EPI == 2) acc = acc + bias[col];
        C[(size_t)row * N + col] = acc;
    }
}

// ---------------- fused attention (flash-style, one wave per q row) ----------------
// heads: [q, b, 1140]  (q @ 0, k @ +380, v @ +760), rk: [2049, 380]
// vec out: [q*BSZ+b, 380]
__global__ __launch_bounds__(256)
void attn_kernel(const float* __restrict__ heads, const float* __restrict__ rk,
                 const float* __restrict__ rwb, const float* __restrict__ rrb,
                 const int* __restrict__ relpos, float* __restrict__ vec) {
    const int qbase = blockIdx.x * 4;
    const int b = blockIdx.y;
    const int n = blockIdx.z;
    const int tid = threadIdx.x;
    const int wid = tid >> 6, lane = tid & 63;
    const int qi = qbase + wid;

    __shared__ float Kt[64][DH];
    __shared__ float Vt[64][DH];
    __shared__ float qw[4][DH], qr[4][DH];
    __shared__ float pl[4][64];

    if (lane < DH) {
        float qv = heads[(size_t)(qi * BSZ + b) * H3 + n * DH + lane];
        qw[wid][lane] = qv + rwb[n * DH + lane];
        qr[wid][lane] = qv + rrb[n * DH + lane];
    }
    __syncthreads();

    float m = -INFINITY, l = 0.f, o = 0.f;
    const int ntiles = (qbase + 4 + 63) >> 6;
    const int* rp_row = relpos + ((size_t)b * QLEN + qi) * QLEN;

    for (int kt = 0; kt < ntiles; ++kt) {
        __syncthreads();
        for (int e = tid; e < 64 * DH; e += 256) {
            int kr = e / DH, d = e - kr * DH;
            size_t base = (size_t)((kt * 64 + kr) * BSZ + b) * H3 + n * DH + d;
            Kt[kr][d] = heads[base + 380];
            Vt[kr][d] = heads[base + 760];
        }
        __syncthreads();

        const int kk = kt * 64 + lane;
        const bool act = (kk <= qi);
        float s = -INFINITY;
        if (act) {
            int rpv = rp_row[kk];
            rpv = rpv < -1024 ? -1024 : (rpv > 1024 ? 1024 : rpv);
            const int j = 1024 - rpv;           // 0..2048
            const float* rkrow = rk + (size_t)j * DM + n * DH;
            float s1 = 0.f, s2 = 0.f;
            #pragma unroll
            for (int d = 0; d < DH; ++d) {
                s1 += qw[wid][d] * Kt[lane][d];
                s2 += qr[wid][d] * rkrow[d];
            }
            s = (s1 + s2) * SCALE;
        }
        float pm = s;
        #pragma unroll
        for (int off = 32; off; off >>= 1) pm = fmaxf(pm, __shfl_xor(pm, off, 64));
        const float nm = fmaxf(m, pm);
        const float p = act ? __expf(s - nm) : 0.f;
        const float corr = __expf(m - nm);      // tile 0: exp(-inf) = 0
        float ps = p;
        #pragma unroll
        for (int off = 32; off; off >>= 1) ps += __shfl_xor(ps, off, 64);
        l = l * corr + ps;
        pl[wid][lane] = p;
        m = nm;
        if (lane < DH) {
            float acc = o * corr;
            #pragma unroll 8
            for (int k2 = 0; k2 < 64; ++k2) acc += pl[wid][k2] * Vt[k2][lane];
            o = acc;
        }
    }
    if (lane < DH)
        vec[(size_t)(qi * BSZ + b) * DM + n * DH + lane] = o / l;
}

// ---------------- residual + LayerNorm:  out = LN(x1 + x2) * g + b ----------------
__global__ __launch_bounds__(256)
void ln_kernel(const float* __restrict__ x1, const float* __restrict__ x2,
               const float* __restrict__ g, const float* __restrict__ bb,
               float* __restrict__ out) {
    const int row = blockIdx.x;
    const float* p1 = x1 + (size_t)row * DM;
    const float* p2 = x2 + (size_t)row * DM;
    __shared__ float xb[DM];
    __shared__ float red[256];
    const int tid = threadIdx.x;
    float s = 0.f;
    for (int i = tid; i < DM; i += 256) { float v = p1[i] + p2[i]; xb[i] = v; s += v; }
    red[tid] = s; __syncthreads();
    for (int st = 128; st > 0; st >>= 1) { if (tid < st) red[tid] += red[tid + st]; __syncthreads(); }
    const float mean = red[0] / DM;
    __syncthreads();
    float s2 = 0.f;
    for (int i = tid; i < DM; i += 256) { float d = xb[i] - mean; s2 += d * d; }
    red[tid] = s2; __syncthreads();
    for (int st = 128; st > 0; st >>= 1) { if (tid < st) red[tid] += red[tid + st]; __syncthreads(); }
    const float rstd = rsqrtf(red[0] / DM + 1e-5f);
    for (int i = tid; i < DM; i += 256)
        out[(size_t)row * DM + i] = (xb[i] - mean) * rstd * g[i] + bb[i];
}

extern "C" void kernel_launch(void* const* d_in, const int* in_sizes, int n_in,
                              void* d_out, int out_size, void* d_ws, size_t ws_size,
                              hipStream_t stream) {
    const float* w     = (const float*)d_in[0];
    const float* r     = (const float*)d_in[1];
    const float* rwb   = (const float*)d_in[2];
    const float* rrb   = (const float*)d_in[3];
    const float* qkv_w = (const float*)d_in[4];
    const float* r_w   = (const float*)d_in[5];
    const float* o_w   = (const float*)d_in[6];
    const float* ln1g  = (const float*)d_in[7];
    const float* ln1b  = (const float*)d_in[8];
    const float* ffw1  = (const float*)d_in[9];
    const float* ffb1  = (const float*)d_in[10];
    const float* ffw2  = (const float*)d_in[11];
    const float* ffb2  = (const float*)d_in[12];
    const float* ln2g  = (const float*)d_in[13];
    const float* ln2b  = (const float*)d_in[14];
    const int*   relpos = (const int*)d_in[16];
    float* out = (float*)d_out;

    float* ws    = (float*)d_ws;
    float* heads = ws;                        // 4096*1140
    float* rk    = heads + (size_t)4096 * H3; // 2049*380
    float* vec   = rk    + (size_t)RLEN * DM; // 4096*380
    float* attn  = vec   + (size_t)4096 * DM; // 4096*380
    float* out1  = attn  + (size_t)4096 * DM; // 4096*380
    float* h1    = out1  + (size_t)4096 * DM; // 4096*900
    float* core  = h1    + (size_t)4096 * DI; // 4096*380

    dim3 blk(16, 16);
    // heads = w @ qkv_w^T   [4096,1140]
    gemm_abt<0><<<dim3((H3 + 15) / 16, 256), blk, 0, stream>>>(w, qkv_w, nullptr, heads, 4096, H3, DM);
    // rk = r @ r_w^T        [2049,380]
    gemm_abt<0><<<dim3(24, (RLEN + 15) / 16), blk, 0, stream>>>(r, r_w, nullptr, rk, RLEN, DM, DM);
    // attention -> vec      [4096,380]
    attn_kernel<<<dim3(QLEN / 4, BSZ, NH), 256, 0, stream>>>(heads, rk, rwb, rrb, relpos, vec);
    // attn_out = vec @ o_w^T
    gemm_abt<0><<<dim3(24, 256), blk, 0, stream>>>(vec, o_w, nullptr, attn, 4096, DM, DM);
    // out1 = LN(w + attn_out)
    ln_kernel<<<4096, 256, 0, stream>>>(w, attn, ln1g, ln1b, out1);
    // h1 = relu(out1 @ ff_w1^T + b1)
    gemm_abt<1><<<dim3((DI + 15) / 16, 256), blk, 0, stream>>>(out1, ffw1, ffb1, h1, 4096, DI, DM);
    // core = h1 @ ff_w2^T + b2
    gemm_abt<2><<<dim3(24, 256), blk, 0, stream>>>(h1, ffw2, ffb2, core, 4096, DM, DI);
    // out = LN(out1 + core)
    ln_kernel<<<4096, 256, 0, stream>>>(out1, core, ln2g, ln2b, out);
}

// Round 5
// 664.139 us; speedup vs baseline: 1.7288x; 1.7288x over previous
//
#include <hip/hip_runtime.h>
#include <math.h>

#define QLEN 1024
#define BSZ 4
#define NH 10
#define DH 38
#define DM 380
#define DI 900
#define H3 1140
#define RLEN 2049
#define SCALE 0.16222142113076254f   // 1/sqrt(38)

typedef unsigned short ushortt;
typedef __attribute__((ext_vector_type(8))) short short8;
typedef __attribute__((ext_vector_type(4))) float float4v;

__device__ __forceinline__ float bf2f(ushortt u) {
    return __uint_as_float(((unsigned int)u) << 16);
}
__device__ __forceinline__ ushortt f2bf(float f) {
    unsigned int u = __float_as_uint(f);
    u += 0x7fffu + ((u >> 16) & 1u);   // RNE
    return (ushortt)(u >> 16);
}

// ---------- f32 [R][C] -> bf16 [Rp][Cp], zero-padded ----------
__global__ __launch_bounds__(256)
void convpad(const float* __restrict__ src, ushortt* __restrict__ dst,
             int R, int C, int Rp, int Cp) {
    const int total = Rp * Cp;
    for (int i = blockIdx.x * 256 + threadIdx.x; i < total; i += gridDim.x * 256) {
        int r = i / Cp, c = i - r * Cp;
        float v = (r < R && c < C) ? src[(size_t)r * C + c] : 0.f;
        dst[i] = f2bf(v);
    }
}

// zero the d=38,39 pads of rkp[10][2049][40]
__global__ __launch_bounds__(256)
void rkp_padzero(float* __restrict__ rkp) {
    int i = blockIdx.x * 256 + threadIdx.x;
    if (i < NH * RLEN * 2) {
        int nj = i >> 1;
        rkp[(size_t)nj * 40 + 38 + (i & 1)] = 0.f;
    }
}

// ---------------- bf16 MFMA GEMM:  C[M,N] = A[M,Kp] * B[N,Kp]^T ----------------
// A: bf16 [Mp][Kp] (Mp >= gridM*128), B: bf16 [Np][Kp] (Np >= gridN*64), Kp % 32 == 0.
// EPI: 0 = f32 store, 1 = bf16 store, 2 = rk scatter to rkp[10][2049][40],
//      3 = relu(x+bias) -> bf16 (FF1, fixed ld 928, zero cols 900..927),
//      4 = x+bias -> f32
template<int EPI>
__global__ __launch_bounds__(256)
void gemm_mfma(const ushortt* __restrict__ A, const ushortt* __restrict__ B,
               const float* __restrict__ bias, void* __restrict__ Cout,
               int M, int N, int Kp, int ldc) {
    __shared__ __align__(16) ushortt As[128 * 32];
    __shared__ __align__(16) ushortt Bs[64 * 32];
    const int tid = threadIdx.x;
    const int wid = tid >> 6, lane = tid & 63;
    const int bRow = blockIdx.y * 128, bCol = blockIdx.x * 64;

    float4v acc[2][4];
    const float4v zz = {0.f, 0.f, 0.f, 0.f};
    #pragma unroll
    for (int m = 0; m < 2; ++m)
        #pragma unroll
        for (int n = 0; n < 4; ++n) acc[m][n] = zz;

    const int arow = tid >> 1, acol = (tid & 1) * 16;  // 2x16B per thread (A)
    const int brow = tid >> 2, bcol = (tid & 3) * 8;   // 1x16B per thread (B)
    const int fr = lane & 15, kg = lane >> 4;

    for (int k0 = 0; k0 < Kp; k0 += 32) {
        const ushortt* ag = A + (size_t)(bRow + arow) * Kp + k0 + acol;
        float4v a0 = *(const float4v*)ag;
        float4v a1 = *(const float4v*)(ag + 8);
        const ushortt* bg = B + (size_t)(bCol + brow) * Kp + k0 + bcol;
        float4v b0 = *(const float4v*)bg;
        __syncthreads();
        *(float4v*)&As[arow * 32 + acol] = a0;
        *(float4v*)&As[arow * 32 + acol + 8] = a1;
        *(float4v*)&Bs[brow * 32 + bcol] = b0;
        __syncthreads();

        short8 bf[4];
        #pragma unroll
        for (int n = 0; n < 4; ++n)
            bf[n] = *(const short8*)&Bs[(n * 16 + fr) * 32 + kg * 8];
        #pragma unroll
        for (int m = 0; m < 2; ++m) {
            short8 af = *(const short8*)&As[(wid * 32 + m * 16 + fr) * 32 + kg * 8];
            #pragma unroll
            for (int n = 0; n < 4; ++n)
                acc[m][n] = __builtin_amdgcn_mfma_f32_16x16x32_bf16(af, bf[n], acc[m][n], 0, 0, 0);
        }
    }

    #pragma unroll
    for (int m = 0; m < 2; ++m)
        #pragma unroll
        for (int n = 0; n < 4; ++n)
            #pragma unroll
            for (int j = 0; j < 4; ++j) {
                const int row = bRow + wid * 32 + m * 16 + (lane >> 4) * 4 + j;
                const int col = bCol + n * 16 + (lane & 15);
                const float v = acc[m][n][j];
                if (EPI == 0) {
                    if (row < M && col < N) ((float*)Cout)[(size_t)row * ldc + col] = v;
                } else if (EPI == 1) {
                    if (row < M && col < N) ((ushortt*)Cout)[(size_t)row * ldc + col] = f2bf(v);
                } else if (EPI == 2) {
                    if (row < M && col < N) {
                        int nh = col / DH, d = col - nh * DH;
                        ((float*)Cout)[((size_t)nh * RLEN + row) * 40 + d] = v;
                    }
                } else if (EPI == 3) {
                    if (row < M && col < 928) {
                        float h = (col < DI) ? fmaxf(v + bias[col], 0.f) : 0.f;
                        ((ushortt*)Cout)[(size_t)row * 928 + col] = f2bf(h);
                    }
                } else {
                    if (row < M && col < N) ((float*)Cout)[(size_t)row * ldc + col] = v + bias[col];
                }
            }
}

// ---------------- fused attention (flash-style, one wave per q row) ----------------
// hb: bf16 heads [q*4+b][1140] (q@0, k@+380, v@+760); rkp: f32 [10][2049][40]
// vec out: bf16 [q*4+b][384] (cols 380..383 zeroed)
__global__ __launch_bounds__(256)
void attn_kernel(const ushortt* __restrict__ hb, const float* __restrict__ rkp,
                 const float* __restrict__ rwb, const float* __restrict__ rrb,
                 const int* __restrict__ relpos, ushortt* __restrict__ vec) {
    const int qbase = blockIdx.x * 4;
    const int b = blockIdx.y;
    const int n = blockIdx.z;
    const int tid = threadIdx.x;
    const int wid = tid >> 6, lane = tid & 63;
    const int qi = qbase + wid;

    __shared__ __align__(16) float Kt[64][44];
    __shared__ __align__(16) float Vt[64][44];
    __shared__ __align__(16) float qw[4][44], qr[4][44];
    __shared__ float pl[4][64];

    if (lane < 44) {
        float qv = 0.f, wv = 0.f, rv = 0.f;
        if (lane < DH) {
            qv = bf2f(hb[(size_t)(qi * BSZ + b) * H3 + n * DH + lane]);
            wv = rwb[n * DH + lane];
            rv = rrb[n * DH + lane];
        }
        qw[wid][lane] = (lane < DH) ? qv + wv : 0.f;
        qr[wid][lane] = (lane < DH) ? qv + rv : 0.f;
    }
    // zero K/V pad columns (written once; staging never touches d>=38)
    for (int e = tid; e < 64 * 6; e += 256) {
        int r = e / 6, c = 38 + e % 6;
        Kt[r][c] = 0.f; Vt[r][c] = 0.f;
    }
    __syncthreads();

    float m = -INFINITY, l = 0.f, o = 0.f;
    const int ntiles = (qbase + 4 + 63) >> 6;
    const int* rp_row = relpos + ((size_t)b * QLEN + qi) * QLEN;

    for (int kt = 0; kt < ntiles; ++kt) {
        __syncthreads();
        for (int e = tid; e < 64 * DH; e += 256) {
            int kr = e / DH, d = e - kr * DH;
            size_t base = (size_t)((kt * 64 + kr) * BSZ + b) * H3 + n * DH + d;
            Kt[kr][d] = bf2f(hb[base + 380]);
            Vt[kr][d] = bf2f(hb[base + 760]);
        }
        __syncthreads();

        const int kk = kt * 64 + lane;
        const bool act = (kk <= qi);
        float s = -INFINITY;
        if (act) {
            int rpv = rp_row[kk];
            rpv = rpv < -1024 ? -1024 : (rpv > 1024 ? 1024 : rpv);
            const int j = 1024 - rpv;                    // 0..2048
            const float4v* rk4 = (const float4v*)(rkp + ((size_t)n * RLEN + j) * 40);
            const float4v* qw4 = (const float4v*)&qw[wid][0];
            const float4v* qr4 = (const float4v*)&qr[wid][0];
            const float4v* kt4 = (const float4v*)&Kt[lane][0];
            float4v v1 = {0.f, 0.f, 0.f, 0.f}, v2 = {0.f, 0.f, 0.f, 0.f};
            #pragma unroll
            for (int i = 0; i < 10; ++i) {
                v1 += qw4[i] * kt4[i];
                v2 += qr4[i] * rk4[i];
            }
            v1 += qw4[10] * kt4[10];
            s = ((v1[0] + v1[1] + v1[2] + v1[3]) + (v2[0] + v2[1] + v2[2] + v2[3])) * SCALE;
        }
        float pm = s;
        #pragma unroll
        for (int off = 32; off; off >>= 1) pm = fmaxf(pm, __shfl_xor(pm, off, 64));
        const float nm = fmaxf(m, pm);
        const float p = act ? __expf(s - nm) : 0.f;
        const float corr = __expf(m - nm);
        float ps = p;
        #pragma unroll
        for (int off = 32; off; off >>= 1) ps += __shfl_xor(ps, off, 64);
        l = l * corr + ps;
        pl[wid][lane] = p;
        m = nm;
        if (lane < DH) {
            float acc = o * corr;
            #pragma unroll 8
            for (int k2 = 0; k2 < 64; ++k2) acc += pl[wid][k2] * Vt[k2][lane];
            o = acc;
        }
    }
    const size_t vrow = (size_t)(qi * BSZ + b) * 384;
    if (lane < DH) vec[vrow + n * DH + lane] = f2bf(o / l);
    else if (n == NH - 1 && lane < 42) vec[vrow + 342 + lane] = 0;  // cols 380..383
}

// ---------------- residual + LayerNorm ----------------
template<bool WRITE_BF>
__global__ __launch_bounds__(256)
void ln_kernel(const float* __restrict__ x1, const float* __restrict__ x2,
               const float* __restrict__ g, const float* __restrict__ bb,
               float* __restrict__ outf, ushortt* __restrict__ outbf) {
    const int row = blockIdx.x;
    const float* p1 = x1 + (size_t)row * DM;
    const float* p2 = x2 + (size_t)row * DM;
    __shared__ float xb[DM];
    __shared__ float red[256];
    const int tid = threadIdx.x;
    float s = 0.f;
    for (int i = tid; i < DM; i += 256) { float v = p1[i] + p2[i]; xb[i] = v; s += v; }
    red[tid] = s; __syncthreads();
    for (int st = 128; st > 0; st >>= 1) { if (tid < st) red[tid] += red[tid + st]; __syncthreads(); }
    const float mean = red[0] / DM;
    __syncthreads();
    float s2 = 0.f;
    for (int i = tid; i < DM; i += 256) { float d = xb[i] - mean; s2 += d * d; }
    red[tid] = s2; __syncthreads();
    for (int st = 128; st > 0; st >>= 1) { if (tid < st) red[tid] += red[tid + st]; __syncthreads(); }
    const float rstd = rsqrtf(red[0] / DM + 1e-5f);
    for (int i = tid; i < (WRITE_BF ? 384 : DM); i += 256) {
        float v = 0.f;
        if (i < DM) {
            v = (xb[i] - mean) * rstd * g[i] + bb[i];
            outf[(size_t)row * DM + i] = v;
        }
        if (WRITE_BF) outbf[(size_t)row * 384 + i] = f2bf(i < DM ? v : 0.f);
    }
}

extern "C" void kernel_launch(void* const* d_in, const int* in_sizes, int n_in,
                              void* d_out, int out_size, void* d_ws, size_t ws_size,
                              hipStream_t stream) {
    const float* w     = (const float*)d_in[0];
    const float* r     = (const float*)d_in[1];
    const float* rwb   = (const float*)d_in[2];
    const float* rrb   = (const float*)d_in[3];
    const float* qkv_w = (const float*)d_in[4];
    const float* r_w   = (const float*)d_in[5];
    const float* o_w   = (const float*)d_in[6];
    const float* ln1g  = (const float*)d_in[7];
    const float* ln1b  = (const float*)d_in[8];
    const float* ffw1  = (const float*)d_in[9];
    const float* ffb1  = (const float*)d_in[10];
    const float* ffw2  = (const float*)d_in[11];
    const float* ffb2  = (const float*)d_in[12];
    const float* ln2g  = (const float*)d_in[13];
    const float* ln2b  = (const float*)d_in[14];
    const int*   relpos = (const int*)d_in[16];
    float* out = (float*)d_out;

    char* cur = (char*)d_ws;
    auto alloc = [&](size_t bytes) { char* p = cur; cur += (bytes + 255) & ~(size_t)255; return p; };
    ushortt* heads_bf = (ushortt*)alloc((size_t)4096 * H3 * 2);
    ushortt* w_bf     = (ushortt*)alloc((size_t)4096 * 384 * 2);
    ushortt* qkv_bf   = (ushortt*)alloc((size_t)1152 * 384 * 2);
    ushortt* r_bf     = (ushortt*)alloc((size_t)2176 * 384 * 2);
    ushortt* rw_bf    = (ushortt*)alloc((size_t)384 * 384 * 2);
    ushortt* ow_bf    = (ushortt*)alloc((size_t)384 * 384 * 2);
    ushortt* f1_bf    = (ushortt*)alloc((size_t)960 * 384 * 2);
    ushortt* f2_bf    = (ushortt*)alloc((size_t)384 * 928 * 2);
    ushortt* vec_bf   = (ushortt*)alloc((size_t)4096 * 384 * 2);
    ushortt* out1_bf  = (ushortt*)alloc((size_t)4096 * 384 * 2);
    ushortt* h1_bf    = (ushortt*)alloc((size_t)4096 * 928 * 2);
    float*   rkp      = (float*)alloc((size_t)NH * RLEN * 40 * 4);
    float*   attnf    = (float*)alloc((size_t)4096 * DM * 4);
    float*   out1f    = (float*)alloc((size_t)4096 * DM * 4);
    float*   core     = (float*)alloc((size_t)4096 * DM * 4);

    auto cgrid = [](size_t total) { return dim3((unsigned)((total + 255) / 256)); };
    // input conversions (f32 -> zero-padded bf16)
    convpad<<<cgrid((size_t)4096 * 384), 256, 0, stream>>>(w, w_bf, 4096, DM, 4096, 384);
    convpad<<<cgrid((size_t)1152 * 384), 256, 0, stream>>>(qkv_w, qkv_bf, H3, DM, 1152, 384);
    convpad<<<cgrid((size_t)2176 * 384), 256, 0, stream>>>(r, r_bf, RLEN, DM, 2176, 384);
    convpad<<<cgrid((size_t)384 * 384), 256, 0, stream>>>(r_w, rw_bf, DM, DM, 384, 384);
    convpad<<<cgrid((size_t)384 * 384), 256, 0, stream>>>(o_w, ow_bf, DM, DM, 384, 384);
    convpad<<<cgrid((size_t)960 * 384), 256, 0, stream>>>(ffw1, f1_bf, DI, DM, 960, 384);
    convpad<<<cgrid((size_t)384 * 928), 256, 0, stream>>>(ffw2, f2_bf, DM, DI, 384, 928);
    rkp_padzero<<<cgrid((size_t)NH * RLEN * 2), 256, 0, stream>>>(rkp);

    // heads(bf16) = w @ qkv_w^T   [4096,1140]
    gemm_mfma<1><<<dim3(18, 32), 256, 0, stream>>>(w_bf, qkv_bf, nullptr, heads_bf, 4096, H3, 384, H3);
    // rkp = (r @ r_w^T) scattered to [10][2049][40]
    gemm_mfma<2><<<dim3(6, 17), 256, 0, stream>>>(r_bf, rw_bf, nullptr, rkp, RLEN, DM, 384, 0);
    // attention -> vec_bf [4096][384]
    attn_kernel<<<dim3(QLEN / 4, BSZ, NH), 256, 0, stream>>>(heads_bf, rkp, rwb, rrb, relpos, vec_bf);
    // attn_out(f32) = vec @ o_w^T
    gemm_mfma<0><<<dim3(6, 32), 256, 0, stream>>>(vec_bf, ow_bf, nullptr, attnf, 4096, DM, 384, DM);
    // out1 = LN(w + attn_out)  (f32 + bf16)
    ln_kernel<true><<<4096, 256, 0, stream>>>(w, attnf, ln1g, ln1b, out1f, out1_bf);
    // h1(bf16) = relu(out1 @ ff_w1^T + b1)   [4096][928]
    gemm_mfma<3><<<dim3(15, 32), 256, 0, stream>>>(out1_bf, f1_bf, ffb1, h1_bf, 4096, DI, 384, 928);
    // core(f32) = h1 @ ff_w2^T + b2
    gemm_mfma<4><<<dim3(6, 32), 256, 0, stream>>>(h1_bf, f2_bf, ffb2, core, 4096, DM, 928, DM);
    // out = LN(out1 + core)
    ln_kernel<false><<<4096, 256, 0, stream>>>(out1f, core, ln2g, ln2b, out, nullptr);
}

// Round 6
// 538.754 us; speedup vs baseline: 2.1312x; 1.2327x over previous
//
#include <hip/hip_runtime.h>
#include <math.h>

#define QLEN 1024
#define BSZ 4
#define NH 10
#define DH 38
#define DM 380
#define DI 900
#define H3 1140
#define RLEN 2049
#define SCALE 0.16222142113076254f   // 1/sqrt(38)

typedef unsigned short ushortt;
typedef __attribute__((ext_vector_type(8))) short short8;
typedef __attribute__((ext_vector_type(4))) float float4v;

__device__ __forceinline__ float bf2f(ushortt u) {
    return __uint_as_float(((unsigned int)u) << 16);
}
__device__ __forceinline__ ushortt f2bf(float f) {
    unsigned int u = __float_as_uint(f);
    u += 0x7fffu + ((u >> 16) & 1u);   // RNE
    return (ushortt)(u >> 16);
}
__device__ __forceinline__ float bfl(unsigned int u) { return __uint_as_float(u << 16); }
__device__ __forceinline__ float bfh(unsigned int u) { return __uint_as_float(u & 0xffff0000u); }

// ---------- f32 [R][C] -> bf16 [Rp][Cp], zero-padded ----------
__global__ __launch_bounds__(256)
void convpad(const float* __restrict__ src, ushortt* __restrict__ dst,
             int R, int C, int Rp, int Cp) {
    const int total = Rp * Cp;
    for (int i = blockIdx.x * 256 + threadIdx.x; i < total; i += gridDim.x * 256) {
        int r = i / Cp, c = i - r * Cp;
        float v = (r < R && c < C) ? src[(size_t)r * C + c] : 0.f;
        dst[i] = f2bf(v);
    }
}

// ---------- zero the pad lanes once per launch ----------
__global__ __launch_bounds__(256)
void init_pads(float* __restrict__ qwp, float* __restrict__ qrp,
               float* __restrict__ Kp, float* __restrict__ Vp,
               ushortt* __restrict__ rkb, ushortt* __restrict__ vec) {
    const int i = blockIdx.x * 256 + threadIdx.x;
    if (i < BSZ * NH * 1024 * 2) {                       // d=38,39 of the 4 head arrays
        size_t idx = (size_t)(i >> 1) * 40 + 38 + (i & 1);
        qwp[idx] = 0.f; qrp[idx] = 0.f; Kp[idx] = 0.f; Vp[idx] = 0.f;
    }
    if (i < NH * RLEN * 2) {                             // rkb pads
        rkb[(size_t)(i >> 1) * 40 + 38 + (i & 1)] = 0;
    }
    if (i < 4096 * 4) {                                  // vec cols 380..383
        vec[(size_t)(i >> 2) * 384 + 380 + (i & 3)] = 0;
    }
}

// ---------------- bf16 MFMA GEMM:  C[M,N] = A[M,Kp] * B[N,Kp]^T ----------------
// EPI: 0 = f32 store, 3 = relu(x+bias)->bf16 (ld 928, zero cols 900..927),
//      4 = x+bias->f32, 5 = QKV scatter (qwp/qrp/Kp/Vp), 6 = rk scatter bf16
template<int EPI>
__global__ __launch_bounds__(256)
void gemm_mfma(const ushortt* __restrict__ A, const ushortt* __restrict__ B,
               const float* __restrict__ bias, void* __restrict__ Cout,
               int M, int N, int Kpp, int ldc,
               const float* __restrict__ bias2, float* __restrict__ out2,
               float* __restrict__ out3, float* __restrict__ out4) {
    __shared__ __align__(16) ushortt As[128 * 32];
    __shared__ __align__(16) ushortt Bs[64 * 32];
    const int tid = threadIdx.x;
    const int wid = tid >> 6, lane = tid & 63;
    const int bRow = blockIdx.y * 128, bCol = blockIdx.x * 64;

    float4v acc[2][4];
    const float4v zz = {0.f, 0.f, 0.f, 0.f};
    #pragma unroll
    for (int m = 0; m < 2; ++m)
        #pragma unroll
        for (int n = 0; n < 4; ++n) acc[m][n] = zz;

    const int arow = tid >> 1, acol = (tid & 1) * 16;
    const int brow = tid >> 2, bcol = (tid & 3) * 8;
    const int fr = lane & 15, kg = lane >> 4;

    for (int k0 = 0; k0 < Kpp; k0 += 32) {
        const ushortt* ag = A + (size_t)(bRow + arow) * Kpp + k0 + acol;
        float4v a0 = *(const float4v*)ag;
        float4v a1 = *(const float4v*)(ag + 8);
        const ushortt* bg = B + (size_t)(bCol + brow) * Kpp + k0 + bcol;
        float4v b0 = *(const float4v*)bg;
        __syncthreads();
        *(float4v*)&As[arow * 32 + acol] = a0;
        *(float4v*)&As[arow * 32 + acol + 8] = a1;
        *(float4v*)&Bs[brow * 32 + bcol] = b0;
        __syncthreads();

        short8 bf[4];
        #pragma unroll
        for (int n = 0; n < 4; ++n)
            bf[n] = *(const short8*)&Bs[(n * 16 + fr) * 32 + kg * 8];
        #pragma unroll
        for (int m = 0; m < 2; ++m) {
            short8 af = *(const short8*)&As[(wid * 32 + m * 16 + fr) * 32 + kg * 8];
            #pragma unroll
            for (int n = 0; n < 4; ++n)
                acc[m][n] = __builtin_amdgcn_mfma_f32_16x16x32_bf16(af, bf[n], acc[m][n], 0, 0, 0);
        }
    }

    #pragma unroll
    for (int m = 0; m < 2; ++m)
        #pragma unroll
        for (int n = 0; n < 4; ++n)
            #pragma unroll
            for (int j = 0; j < 4; ++j) {
                const int row = bRow + wid * 32 + m * 16 + (lane >> 4) * 4 + j;
                const int col = bCol + n * 16 + (lane & 15);
                const float v = acc[m][n][j];
                if (EPI == 0) {
                    if (row < M && col < N) ((float*)Cout)[(size_t)row * ldc + col] = v;
                } else if (EPI == 3) {
                    if (row < M && col < 928) {
                        float h = (col < DI) ? fmaxf(v + bias[col], 0.f) : 0.f;
                        ((ushortt*)Cout)[(size_t)row * 928 + col] = f2bf(h);
                    }
                } else if (EPI == 4) {
                    if (row < M && col < N) ((float*)Cout)[(size_t)row * ldc + col] = v + bias[col];
                } else if (EPI == 5) {
                    if (col < H3) {
                        int part = col / 380;
                        int c = col - part * 380;
                        int nh = c / 38, d = c - nh * 38;
                        int q = row >> 2, b2 = row & 3;
                        size_t idx = (((size_t)b2 * NH + nh) * 1024 + q) * 40 + d;
                        if (part == 0) {
                            ((float*)Cout)[idx] = v + bias[c];   // qwp (+r_w_bias)
                            out2[idx] = v + bias2[c];            // qrp (+r_r_bias)
                        } else if (part == 1) out3[idx] = v;     // Kp
                        else out4[idx] = v;                      // Vp
                    }
                } else {  // EPI 6
                    if (row < M && col < N) {
                        int nh = col / 38, d = col - nh * 38;
                        ((ushortt*)Cout)[((size_t)nh * RLEN + row) * 40 + d] = f2bf(v);
                    }
                }
            }
}

// ---------------- fused attention, 32 q-rows per block ----------------
// qwp/qrp/Kp/Vp: f32 [b][n][1024][40]; rkb: bf16 [n][2049][40]
// vec out: bf16 [q*4+b][384]
__global__ __launch_bounds__(256)
void attn2(const float* __restrict__ qwp, const float* __restrict__ qrp,
           const float* __restrict__ Kp, const float* __restrict__ Vp,
           const ushortt* __restrict__ rkb, const int* __restrict__ relpos,
           ushortt* __restrict__ vec) {
    const int qbase = blockIdx.x * 32;
    const int b = blockIdx.y, n = blockIdx.z;
    const int tid = threadIdx.x;
    const int row = tid >> 3, kg = tid & 7;
    const int qi = qbase + row;

    __shared__ __align__(16) float KtL[64 * 40];
    __shared__ __align__(16) float VtL[64 * 40];
    __shared__ __align__(16) float qrL[32 * 40];
    __shared__ float pL[32 * 66];

    const size_t bn = (size_t)b * NH + n;
    const float* Kbase = Kp + bn * 1024 * 40;
    const float* Vbase = Vp + bn * 1024 * 40;

    // stage qr rows (32x40 f32)
    {
        const float4v* src = (const float4v*)(qrp + (bn * 1024 + qbase) * 40);
        for (int e = tid; e < 320; e += 256) ((float4v*)qrL)[e] = src[e];
    }
    // preload own qw row into registers
    float4v qw[10];
    {
        const float4v* src = (const float4v*)(qwp + (bn * 1024 + qi) * 40);
        #pragma unroll
        for (int i = 0; i < 10; ++i) qw[i] = src[i];
    }
    float o[5] = {0.f, 0.f, 0.f, 0.f, 0.f};
    float mrun = -INFINITY, lrun = 0.f;
    const int* rp = relpos + ((size_t)b * QLEN + qi) * QLEN;
    const ushortt* rkn = rkb + (size_t)n * RLEN * 40;
    const float4v* qr4 = (const float4v*)(qrL + row * 40);
    const int ntiles = (qbase + 95) >> 6;

    for (int kt = 0; kt < ntiles; ++kt) {
        const int k0 = kt * 64;
        __syncthreads();
        {
            const float4v* ks = (const float4v*)(Kbase + (size_t)k0 * 40);
            const float4v* vs = (const float4v*)(Vbase + (size_t)k0 * 40);
            for (int e = tid; e < 640; e += 256) {
                ((float4v*)KtL)[e] = ks[e];
                ((float4v*)VtL)[e] = vs[e];
            }
        }
        __syncthreads();

        float s[8];
        float pmax = -INFINITY;
        #pragma unroll
        for (int ss = 0; ss < 8; ++ss) {
            const int k = kg + ss * 8;
            const int kk = k0 + k;
            float sv = -INFINITY;
            if (kk <= qi) {
                int rpv = rp[kk];
                rpv = rpv < -1024 ? -1024 : (rpv > 1024 ? 1024 : rpv);
                const int j = 1024 - rpv;
                // content dot: qw(reg) . K(LDS)
                float acc1 = 0.f;
                const float4v* kt4 = (const float4v*)(KtL + k * 40);
                #pragma unroll
                for (int i = 0; i < 10; ++i) {
                    float4v kv = kt4[i];
                    acc1 += qw[i][0] * kv[0] + qw[i][1] * kv[1]
                          + qw[i][2] * kv[2] + qw[i][3] * kv[3];
                }
                // position dot: qr(LDS) . rk[j](gathered bf16)
                float acc2 = 0.f;
                const uint4* r16 = (const uint4*)(rkn + (size_t)j * 40);
                #pragma unroll
                for (int i = 0; i < 5; ++i) {
                    uint4 u = r16[i];
                    float4v q0 = qr4[2 * i], q1 = qr4[2 * i + 1];
                    acc2 += q0[0] * bfl(u.x) + q0[1] * bfh(u.x)
                          + q0[2] * bfl(u.y) + q0[3] * bfh(u.y);
                    acc2 += q1[0] * bfl(u.z) + q1[1] * bfh(u.z)
                          + q1[2] * bfl(u.w) + q1[3] * bfh(u.w);
                }
                sv = (acc1 + acc2) * SCALE;
            }
            s[ss] = sv;
            pmax = fmaxf(pmax, sv);
        }
        // row-reduce max over the 8-lane group
        pmax = fmaxf(pmax, __shfl_xor(pmax, 1, 64));
        pmax = fmaxf(pmax, __shfl_xor(pmax, 2, 64));
        pmax = fmaxf(pmax, __shfl_xor(pmax, 4, 64));
        const float nm = fmaxf(mrun, pmax);
        const float corr = __expf(mrun - nm);   // tile 0: exp(-inf)=0
        float psum = 0.f;
        float* prw = pL + row * 66;
        #pragma unroll
        for (int ss = 0; ss < 8; ++ss) {
            float p = __expf(s[ss] - nm);       // s=-inf -> 0
            psum += p;
            prw[kg + ss * 8] = p;
        }
        psum += __shfl_xor(psum, 1, 64);
        psum += __shfl_xor(psum, 2, 64);
        psum += __shfl_xor(psum, 4, 64);
        lrun = lrun * corr + psum;
        mrun = nm;
        #pragma unroll
        for (int jj = 0; jj < 5; ++jj) o[jj] *= corr;
        // PV: same-wave LDS (p written by this row's own 8 lanes)
        int kmax = qi - k0 + 1; if (kmax > 64) kmax = 64;
        #pragma unroll 4
        for (int k = 0; k < kmax; ++k) {
            float p = prw[k];
            const float* vr = VtL + k * 40;
            float4v v4 = *(const float4v*)(vr + 4 * kg);
            float v1 = vr[32 + kg];
            o[0] += p * v4[0]; o[1] += p * v4[1];
            o[2] += p * v4[2]; o[3] += p * v4[3];
            o[4] += p * v1;
        }
    }
    const float inv = 1.f / lrun;
    const size_t vrow = ((size_t)qi * BSZ + b) * 384 + (size_t)n * 38;
    #pragma unroll
    for (int jj = 0; jj < 4; ++jj)
        vec[vrow + 4 * kg + jj] = f2bf(o[jj] * inv);    // d = 4*kg+jj <= 31 < 38
    const int d4 = 32 + kg;
    if (d4 < 38) vec[vrow + d4] = f2bf(o[4] * inv);
}

// ---------------- residual + LayerNorm ----------------
template<bool WRITE_BF>
__global__ __launch_bounds__(256)
void ln_kernel(const float* __restrict__ x1, const float* __restrict__ x2,
               const float* __restrict__ g, const float* __restrict__ bb,
               float* __restrict__ outf, ushortt* __restrict__ outbf) {
    const int row = blockIdx.x;
    const float* p1 = x1 + (size_t)row * DM;
    const float* p2 = x2 + (size_t)row * DM;
    __shared__ float xb[DM];
    __shared__ float red[256];
    const int tid = threadIdx.x;
    float s = 0.f;
    for (int i = tid; i < DM; i += 256) { float v = p1[i] + p2[i]; xb[i] = v; s += v; }
    red[tid] = s; __syncthreads();
    for (int st = 128; st > 0; st >>= 1) { if (tid < st) red[tid] += red[tid + st]; __syncthreads(); }
    const float mean = red[0] / DM;
    __syncthreads();
    float s2 = 0.f;
    for (int i = tid; i < DM; i += 256) { float d = xb[i] - mean; s2 += d * d; }
    red[tid] = s2; __syncthreads();
    for (int st = 128; st > 0; st >>= 1) { if (tid < st) red[tid] += red[tid + st]; __syncthreads(); }
    const float rstd = rsqrtf(red[0] / DM + 1e-5f);
    for (int i = tid; i < (WRITE_BF ? 384 : DM); i += 256) {
        float v = 0.f;
        if (i < DM) {
            v = (xb[i] - mean) * rstd * g[i] + bb[i];
            outf[(size_t)row * DM + i] = v;
        }
        if (WRITE_BF) outbf[(size_t)row * 384 + i] = f2bf(i < DM ? v : 0.f);
    }
}

extern "C" void kernel_launch(void* const* d_in, const int* in_sizes, int n_in,
                              void* d_out, int out_size, void* d_ws, size_t ws_size,
                              hipStream_t stream) {
    const float* w     = (const float*)d_in[0];
    const float* r     = (const float*)d_in[1];
    const float* rwb   = (const float*)d_in[2];
    const float* rrb   = (const float*)d_in[3];
    const float* qkv_w = (const float*)d_in[4];
    const float* r_w   = (const float*)d_in[5];
    const float* o_w   = (const float*)d_in[6];
    const float* ln1g  = (const float*)d_in[7];
    const float* ln1b  = (const float*)d_in[8];
    const float* ffw1  = (const float*)d_in[9];
    const float* ffb1  = (const float*)d_in[10];
    const float* ffw2  = (const float*)d_in[11];
    const float* ffb2  = (const float*)d_in[12];
    const float* ln2g  = (const float*)d_in[13];
    const float* ln2b  = (const float*)d_in[14];
    const int*   relpos = (const int*)d_in[16];
    float* out = (float*)d_out;

    char* cur = (char*)d_ws;
    auto alloc = [&](size_t bytes) { char* p = cur; cur += (bytes + 255) & ~(size_t)255; return p; };
    ushortt* w_bf    = (ushortt*)alloc((size_t)4096 * 384 * 2);
    ushortt* qkv_bf  = (ushortt*)alloc((size_t)1152 * 384 * 2);
    ushortt* r_bf    = (ushortt*)alloc((size_t)2176 * 384 * 2);
    ushortt* rw_bf   = (ushortt*)alloc((size_t)384 * 384 * 2);
    ushortt* ow_bf   = (ushortt*)alloc((size_t)384 * 384 * 2);
    ushortt* f1_bf   = (ushortt*)alloc((size_t)960 * 384 * 2);
    ushortt* f2_bf   = (ushortt*)alloc((size_t)384 * 928 * 2);
    float*   qwp     = (float*)alloc((size_t)BSZ * NH * 1024 * 40 * 4);
    float*   qrp     = (float*)alloc((size_t)BSZ * NH * 1024 * 40 * 4);
    float*   Kpp     = (float*)alloc((size_t)BSZ * NH * 1024 * 40 * 4);
    float*   Vpp     = (float*)alloc((size_t)BSZ * NH * 1024 * 40 * 4);
    ushortt* rkb     = (ushortt*)alloc((size_t)NH * RLEN * 40 * 2);
    ushortt* vec_bf  = (ushortt*)alloc((size_t)4096 * 384 * 2);
    ushortt* out1_bf = (ushortt*)alloc((size_t)4096 * 384 * 2);
    ushortt* h1_bf   = (ushortt*)alloc((size_t)4096 * 928 * 2);
    float*   attnf   = (float*)alloc((size_t)4096 * DM * 4);
    float*   out1f   = (float*)alloc((size_t)4096 * DM * 4);
    float*   core    = (float*)alloc((size_t)4096 * DM * 4);

    auto cgrid = [](size_t total) { return dim3((unsigned)((total + 255) / 256)); };
    convpad<<<cgrid((size_t)4096 * 384), 256, 0, stream>>>(w, w_bf, 4096, DM, 4096, 384);
    convpad<<<cgrid((size_t)1152 * 384), 256, 0, stream>>>(qkv_w, qkv_bf, H3, DM, 1152, 384);
    convpad<<<cgrid((size_t)2176 * 384), 256, 0, stream>>>(r, r_bf, RLEN, DM, 2176, 384);
    convpad<<<cgrid((size_t)384 * 384), 256, 0, stream>>>(r_w, rw_bf, DM, DM, 384, 384);
    convpad<<<cgrid((size_t)384 * 384), 256, 0, stream>>>(o_w, ow_bf, DM, DM, 384, 384);
    convpad<<<cgrid((size_t)960 * 384), 256, 0, stream>>>(ffw1, f1_bf, DI, DM, 960, 384);
    convpad<<<cgrid((size_t)384 * 928), 256, 0, stream>>>(ffw2, f2_bf, DM, DI, 384, 928);
    init_pads<<<cgrid((size_t)BSZ * NH * 1024 * 2), 256, 0, stream>>>(qwp, qrp, Kpp, Vpp, rkb, vec_bf);

    // QKV GEMM with scatter epilogue -> qwp/qrp/Kpp/Vpp
    gemm_mfma<5><<<dim3(18, 32), 256, 0, stream>>>(w_bf, qkv_bf, rwb, qwp, 4096, H3, 384, 0,
                                                   rrb, qrp, Kpp, Vpp);
    // rk GEMM -> rkb (bf16, padded per-head rows)
    gemm_mfma<6><<<dim3(6, 17), 256, 0, stream>>>(r_bf, rw_bf, nullptr, rkb, RLEN, DM, 384, 0,
                                                  nullptr, nullptr, nullptr, nullptr);
    // attention
    attn2<<<dim3(32, BSZ, NH), 256, 0, stream>>>(qwp, qrp, Kpp, Vpp, rkb, relpos, vec_bf);
    // attn_out = vec @ o_w^T
    gemm_mfma<0><<<dim3(6, 32), 256, 0, stream>>>(vec_bf, ow_bf, nullptr, attnf, 4096, DM, 384, DM,
                                                  nullptr, nullptr, nullptr, nullptr);
    ln_kernel<true><<<4096, 256, 0, stream>>>(w, attnf, ln1g, ln1b, out1f, out1_bf);
    gemm_mfma<3><<<dim3(15, 32), 256, 0, stream>>>(out1_bf, f1_bf, ffb1, h1_bf, 4096, DI, 384, 928,
                                                   nullptr, nullptr, nullptr, nullptr);
    gemm_mfma<4><<<dim3(6, 32), 256, 0, stream>>>(h1_bf, f2_bf, ffb2, core, 4096, DM, 928, DM,
                                                  nullptr, nullptr, nullptr, nullptr);
    ln_kernel<false><<<4096, 256, 0, stream>>>(out1f, core, ln2g, ln2b, out, nullptr);
}

// Round 7
// 534.190 us; speedup vs baseline: 2.1494x; 1.0085x over previous
//
#include <hip/hip_runtime.h>
#include <math.h>

#define QLEN 1024
#define BSZ 4
#define NH 10
#define DH 38
#define DM 380
#define DI 900
#define H3 1140
#define RLEN 2049
#define SCALE 0.16222142113076254f   // 1/sqrt(38)
#define KS 2                          // k-splits in attention

typedef unsigned short ushortt;
typedef __attribute__((ext_vector_type(8))) short short8;
typedef __attribute__((ext_vector_type(4))) float float4v;

__device__ __forceinline__ float bf2f(ushortt u) {
    return __uint_as_float(((unsigned int)u) << 16);
}
__device__ __forceinline__ ushortt f2bf(float f) {
    unsigned int u = __float_as_uint(f);
    u += 0x7fffu + ((u >> 16) & 1u);   // RNE
    return (ushortt)(u >> 16);
}
__device__ __forceinline__ float bfl(unsigned int u) { return __uint_as_float(u << 16); }
__device__ __forceinline__ float bfh(unsigned int u) { return __uint_as_float(u & 0xffff0000u); }

// ---------- f32 [R][C] -> bf16 [Rp][Cp], zero-padded ----------
__global__ __launch_bounds__(256)
void convpad(const float* __restrict__ src, ushortt* __restrict__ dst,
             int R, int C, int Rp, int Cp) {
    const int total = Rp * Cp;
    for (int i = blockIdx.x * 256 + threadIdx.x; i < total; i += gridDim.x * 256) {
        int r = i / Cp, c = i - r * Cp;
        float v = (r < R && c < C) ? src[(size_t)r * C + c] : 0.f;
        dst[i] = f2bf(v);
    }
}

// ---------- zero the pad lanes once per launch ----------
__global__ __launch_bounds__(256)
void init_pads(float* __restrict__ qwp, float* __restrict__ qrp,
               float* __restrict__ Kp, float* __restrict__ Vp,
               ushortt* __restrict__ rkb, ushortt* __restrict__ vec) {
    const int i = blockIdx.x * 256 + threadIdx.x;
    if (i < BSZ * NH * 1024 * 2) {                       // d=38,39 of the 4 head arrays
        size_t idx = (size_t)(i >> 1) * 40 + 38 + (i & 1);
        qwp[idx] = 0.f; qrp[idx] = 0.f; Kp[idx] = 0.f; Vp[idx] = 0.f;
    }
    if (i < NH * RLEN * 2) {                             // rkb pads
        rkb[(size_t)(i >> 1) * 40 + 38 + (i & 1)] = 0;
    }
    if (i < 4096 * 4) {                                  // vec cols 380..383
        vec[(size_t)(i >> 2) * 384 + 380 + (i & 3)] = 0;
    }
}

// ---------------- bf16 MFMA GEMM:  C[M,N] = A[M,Kp] * B[N,Kp]^T ----------------
// EPI: 0 = f32 store, 3 = relu(x+bias)->bf16 (ld 928, zero cols 900..927),
//      4 = x+bias->f32, 5 = QKV scatter (qwp/qrp/Kp/Vp), 6 = rk scatter bf16
template<int EPI>
__global__ __launch_bounds__(256)
void gemm_mfma(const ushortt* __restrict__ A, const ushortt* __restrict__ B,
               const float* __restrict__ bias, void* __restrict__ Cout,
               int M, int N, int Kpp, int ldc,
               const float* __restrict__ bias2, float* __restrict__ out2,
               float* __restrict__ out3, float* __restrict__ out4) {
    __shared__ __align__(16) ushortt As[128 * 32];
    __shared__ __align__(16) ushortt Bs[64 * 32];
    const int tid = threadIdx.x;
    const int wid = tid >> 6, lane = tid & 63;
    const int bRow = blockIdx.y * 128, bCol = blockIdx.x * 64;

    float4v acc[2][4];
    const float4v zz = {0.f, 0.f, 0.f, 0.f};
    #pragma unroll
    for (int m = 0; m < 2; ++m)
        #pragma unroll
        for (int n = 0; n < 4; ++n) acc[m][n] = zz;

    const int arow = tid >> 1, acol = (tid & 1) * 16;
    const int brow = tid >> 2, bcol = (tid & 3) * 8;
    const int fr = lane & 15, kg = lane >> 4;

    for (int k0 = 0; k0 < Kpp; k0 += 32) {
        const ushortt* ag = A + (size_t)(bRow + arow) * Kpp + k0 + acol;
        float4v a0 = *(const float4v*)ag;
        float4v a1 = *(const float4v*)(ag + 8);
        const ushortt* bg = B + (size_t)(bCol + brow) * Kpp + k0 + bcol;
        float4v b0 = *(const float4v*)bg;
        __syncthreads();
        *(float4v*)&As[arow * 32 + acol] = a0;
        *(float4v*)&As[arow * 32 + acol + 8] = a1;
        *(float4v*)&Bs[brow * 32 + bcol] = b0;
        __syncthreads();

        short8 bf[4];
        #pragma unroll
        for (int n = 0; n < 4; ++n)
            bf[n] = *(const short8*)&Bs[(n * 16 + fr) * 32 + kg * 8];
        #pragma unroll
        for (int m = 0; m < 2; ++m) {
            short8 af = *(const short8*)&As[(wid * 32 + m * 16 + fr) * 32 + kg * 8];
            #pragma unroll
            for (int n = 0; n < 4; ++n)
                acc[m][n] = __builtin_amdgcn_mfma_f32_16x16x32_bf16(af, bf[n], acc[m][n], 0, 0, 0);
        }
    }

    #pragma unroll
    for (int m = 0; m < 2; ++m)
        #pragma unroll
        for (int n = 0; n < 4; ++n)
            #pragma unroll
            for (int j = 0; j < 4; ++j) {
                const int row = bRow + wid * 32 + m * 16 + (lane >> 4) * 4 + j;
                const int col = bCol + n * 16 + (lane & 15);
                const float v = acc[m][n][j];
                if (EPI == 0) {
                    if (row < M && col < N) ((float*)Cout)[(size_t)row * ldc + col] = v;
                } else if (EPI == 3) {
                    if (row < M && col < 928) {
                        float h = (col < DI) ? fmaxf(v + bias[col], 0.f) : 0.f;
                        ((ushortt*)Cout)[(size_t)row * 928 + col] = f2bf(h);
                    }
                } else if (EPI == 4) {
                    if (row < M && col < N) ((float*)Cout)[(size_t)row * ldc + col] = v + bias[col];
                } else if (EPI == 5) {
                    if (col < H3) {
                        int part = col / 380;
                        int c = col - part * 380;
                        int nh = c / 38, d = c - nh * 38;
                        int q = row >> 2, b2 = row & 3;
                        size_t idx = (((size_t)b2 * NH + nh) * 1024 + q) * 40 + d;
                        if (part == 0) {
                            ((float*)Cout)[idx] = v + bias[c];   // qwp (+r_w_bias)
                            out2[idx] = v + bias2[c];            // qrp (+r_r_bias)
                        } else if (part == 1) out3[idx] = v;     // Kp
                        else out4[idx] = v;                      // Vp
                    }
                } else {  // EPI 6
                    if (row < M && col < N) {
                        int nh = col / 38, d = col - nh * 38;
                        ((ushortt*)Cout)[((size_t)nh * RLEN + row) * 40 + d] = f2bf(v);
                    }
                }
            }
}

// ---------------- split-K fused attention, 32 q-rows per block ----------------
// qwp/qrp/Kp/Vp: f32 [b][n][1024][40]; rkb: bf16 [n][2049][40]
// partials: op[s][b*NH+n][1024][40] f32 (unnormalized), ml[s][b*NH+n][1024] {m,l}
__global__ __launch_bounds__(256)
void attn3(const float* __restrict__ qwp, const float* __restrict__ qrp,
           const float* __restrict__ Kp, const float* __restrict__ Vp,
           const ushortt* __restrict__ rkb, const int* __restrict__ relpos,
           float* __restrict__ op, float2* __restrict__ ml) {
    const int qc = 31 - blockIdx.x;              // heavy chunks dispatch first
    const int qbase = qc * 32;
    const int b = blockIdx.y;
    const int n = blockIdx.z % NH, s = blockIdx.z / NH;
    const int tid = threadIdx.x;
    const int row = tid >> 3, kg = tid & 7;
    const int qi = qbase + row;
    const size_t bn = (size_t)b * NH + n;
    const size_t prow = ((size_t)s * (BSZ * NH) + bn) * 1024 + qi;

    const int ntchunk = (qbase + 95) >> 6;       // ceil((qbase+32)/64)
    const int tbeg = s * 8;                      // KS=2: 8 tiles (=512 k) per split
    const int tend = min(tbeg + 8, ntchunk);
    if (tbeg >= tend) {                          // inactive split
        if (kg == 0) ml[prow] = make_float2(-INFINITY, 0.f);
        return;
    }

    __shared__ __align__(16) float KtL[64 * 40];
    __shared__ __align__(16) float VtL[64 * 40];
    __shared__ __align__(16) float qrL[32 * 40];
    __shared__ float pL[32 * 66];

    const float* Kbase = Kp + bn * 1024 * 40;
    const float* Vbase = Vp + bn * 1024 * 40;

    // stage qr rows (32x40 f32)
    {
        const float4v* src = (const float4v*)(qrp + (bn * 1024 + qbase) * 40);
        for (int e = tid; e < 320; e += 256) ((float4v*)qrL)[e] = src[e];
    }
    // preload own qw row into registers
    float4v qw[10];
    {
        const float4v* src = (const float4v*)(qwp + (bn * 1024 + qi) * 40);
        #pragma unroll
        for (int i = 0; i < 10; ++i) qw[i] = src[i];
    }
    float o[5] = {0.f, 0.f, 0.f, 0.f, 0.f};
    float mrun = -INFINITY, lrun = 0.f;
    const int* rp = relpos + ((size_t)b * QLEN + qi) * QLEN;
    const ushortt* rkn = rkb + (size_t)n * RLEN * 40;
    const float4v* qr4 = (const float4v*)(qrL + row * 40);

    for (int kt = tbeg; kt < tend; ++kt) {
        const int k0 = kt * 64;
        __syncthreads();
        {
            const float4v* ks = (const float4v*)(Kbase + (size_t)k0 * 40);
            const float4v* vs = (const float4v*)(Vbase + (size_t)k0 * 40);
            for (int e = tid; e < 640; e += 256) {
                ((float4v*)KtL)[e] = ks[e];
                ((float4v*)VtL)[e] = vs[e];
            }
        }
        __syncthreads();

        float sarr[8];
        float pmax = -INFINITY;
        #pragma unroll
        for (int ss = 0; ss < 8; ++ss) {
            const int k = kg + ss * 8;
            const int kk = k0 + k;
            float sv = -INFINITY;
            if (kk <= qi) {
                int rpv = rp[kk];
                rpv = rpv < -1024 ? -1024 : (rpv > 1024 ? 1024 : rpv);
                const int j = 1024 - rpv;
                float acc1 = 0.f;
                const float4v* kt4 = (const float4v*)(KtL + k * 40);
                #pragma unroll
                for (int i = 0; i < 10; ++i) {
                    float4v kv = kt4[i];
                    acc1 += qw[i][0] * kv[0] + qw[i][1] * kv[1]
                          + qw[i][2] * kv[2] + qw[i][3] * kv[3];
                }
                float acc2 = 0.f;
                const uint4* r16 = (const uint4*)(rkn + (size_t)j * 40);
                #pragma unroll
                for (int i = 0; i < 5; ++i) {
                    uint4 u = r16[i];
                    float4v q0 = qr4[2 * i], q1 = qr4[2 * i + 1];
                    acc2 += q0[0] * bfl(u.x) + q0[1] * bfh(u.x)
                          + q0[2] * bfl(u.y) + q0[3] * bfh(u.y);
                    acc2 += q1[0] * bfl(u.z) + q1[1] * bfh(u.z)
                          + q1[2] * bfl(u.w) + q1[3] * bfh(u.w);
                }
                sv = (acc1 + acc2) * SCALE;
            }
            sarr[ss] = sv;
            pmax = fmaxf(pmax, sv);
        }
        pmax = fmaxf(pmax, __shfl_xor(pmax, 1, 64));
        pmax = fmaxf(pmax, __shfl_xor(pmax, 2, 64));
        pmax = fmaxf(pmax, __shfl_xor(pmax, 4, 64));
        const float nm = fmaxf(mrun, pmax);
        const float corr = __expf(mrun - nm);   // first tile: exp(-inf)=0
        float psum = 0.f;
        float* prw = pL + row * 66;
        #pragma unroll
        for (int ss = 0; ss < 8; ++ss) {
            float p = __expf(sarr[ss] - nm);
            psum += p;
            prw[kg + ss * 8] = p;
        }
        psum += __shfl_xor(psum, 1, 64);
        psum += __shfl_xor(psum, 2, 64);
        psum += __shfl_xor(psum, 4, 64);
        lrun = lrun * corr + psum;
        mrun = nm;
        #pragma unroll
        for (int jj = 0; jj < 5; ++jj) o[jj] *= corr;
        int kmax = qi - k0 + 1; if (kmax > 64) kmax = 64;
        #pragma unroll 4
        for (int k = 0; k < kmax; ++k) {
            float p = prw[k];
            const float* vr = VtL + k * 40;
            float4v v4 = *(const float4v*)(vr + 4 * kg);
            float v1 = vr[32 + kg];
            o[0] += p * v4[0]; o[1] += p * v4[1];
            o[2] += p * v4[2]; o[3] += p * v4[3];
            o[4] += p * v1;
        }
    }
    // write unnormalized partials
    float* oprow = op + prow * 40;
    #pragma unroll
    for (int jj = 0; jj < 4; ++jj) oprow[4 * kg + jj] = o[jj];
    oprow[32 + kg] = o[4];
    if (kg == 0) ml[prow] = make_float2(mrun, lrun);
}

// ---------------- combine split-K partials -> vec (bf16) ----------------
__global__ __launch_bounds__(256)
void attn_combine(const float* __restrict__ op, const float2* __restrict__ ml,
                  ushortt* __restrict__ vec) {
    const int idx = blockIdx.x * 256 + threadIdx.x;
    if (idx >= BSZ * NH * 1024 * 38) return;
    const int d = idx % 38;
    const int rh = idx / 38;                 // bn*1024 + q
    const int q = rh & 1023;
    const int bn = rh >> 10;
    const int b = bn / NH, n = bn - b * NH;
    const float2 a = ml[rh];
    const float2 c = ml[(size_t)BSZ * NH * 1024 + rh];
    const float M = fmaxf(a.x, c.x);         // split 0 always active -> finite
    float l = 0.f, o = 0.f;
    if (a.y > 0.f) {
        float w = __expf(a.x - M);
        l += a.y * w;
        o += op[(size_t)rh * 40 + d] * w;
    }
    if (c.y > 0.f) {
        float w = __expf(c.x - M);
        l += c.y * w;
        o += op[((size_t)BSZ * NH * 1024 + rh) * 40 + d] * w;
    }
    vec[((size_t)q * BSZ + b) * 384 + (size_t)n * 38 + d] = f2bf(o / l);
}

// ---------------- residual + LayerNorm ----------------
template<bool WRITE_BF>
__global__ __launch_bounds__(256)
void ln_kernel(const float* __restrict__ x1, const float* __restrict__ x2,
               const float* __restrict__ g, const float* __restrict__ bb,
               float* __restrict__ outf, ushortt* __restrict__ outbf) {
    const int row = blockIdx.x;
    const float* p1 = x1 + (size_t)row * DM;
    const float* p2 = x2 + (size_t)row * DM;
    __shared__ float xb[DM];
    __shared__ float red[256];
    const int tid = threadIdx.x;
    float s = 0.f;
    for (int i = tid; i < DM; i += 256) { float v = p1[i] + p2[i]; xb[i] = v; s += v; }
    red[tid] = s; __syncthreads();
    for (int st = 128; st > 0; st >>= 1) { if (tid < st) red[tid] += red[tid + st]; __syncthreads(); }
    const float mean = red[0] / DM;
    __syncthreads();
    float s2 = 0.f;
    for (int i = tid; i < DM; i += 256) { float d = xb[i] - mean; s2 += d * d; }
    red[tid] = s2; __syncthreads();
    for (int st = 128; st > 0; st >>= 1) { if (tid < st) red[tid] += red[tid + st]; __syncthreads(); }
    const float rstd = rsqrtf(red[0] / DM + 1e-5f);
    for (int i = tid; i < (WRITE_BF ? 384 : DM); i += 256) {
        float v = 0.f;
        if (i < DM) {
            v = (xb[i] - mean) * rstd * g[i] + bb[i];
            outf[(size_t)row * DM + i] = v;
        }
        if (WRITE_BF) outbf[(size_t)row * 384 + i] = f2bf(i < DM ? v : 0.f);
    }
}

extern "C" void kernel_launch(void* const* d_in, const int* in_sizes, int n_in,
                              void* d_out, int out_size, void* d_ws, size_t ws_size,
                              hipStream_t stream) {
    const float* w     = (const float*)d_in[0];
    const float* r     = (const float*)d_in[1];
    const float* rwb   = (const float*)d_in[2];
    const float* rrb   = (const float*)d_in[3];
    const float* qkv_w = (const float*)d_in[4];
    const float* r_w   = (const float*)d_in[5];
    const float* o_w   = (const float*)d_in[6];
    const float* ln1g  = (const float*)d_in[7];
    const float* ln1b  = (const float*)d_in[8];
    const float* ffw1  = (const float*)d_in[9];
    const float* ffb1  = (const float*)d_in[10];
    const float* ffw2  = (const float*)d_in[11];
    const float* ffb2  = (const float*)d_in[12];
    const float* ln2g  = (const float*)d_in[13];
    const float* ln2b  = (const float*)d_in[14];
    const int*   relpos = (const int*)d_in[16];
    float* out = (float*)d_out;

    char* cur = (char*)d_ws;
    auto alloc = [&](size_t bytes) { char* p = cur; cur += (bytes + 255) & ~(size_t)255; return p; };
    ushortt* w_bf    = (ushortt*)alloc((size_t)4096 * 384 * 2);
    ushortt* qkv_bf  = (ushortt*)alloc((size_t)1152 * 384 * 2);
    ushortt* r_bf    = (ushortt*)alloc((size_t)2176 * 384 * 2);
    ushortt* rw_bf   = (ushortt*)alloc((size_t)384 * 384 * 2);
    ushortt* ow_bf   = (ushortt*)alloc((size_t)384 * 384 * 2);
    ushortt* f1_bf   = (ushortt*)alloc((size_t)960 * 384 * 2);
    ushortt* f2_bf   = (ushortt*)alloc((size_t)384 * 928 * 2);
    float*   qwp     = (float*)alloc((size_t)BSZ * NH * 1024 * 40 * 4);
    float*   qrp     = (float*)alloc((size_t)BSZ * NH * 1024 * 40 * 4);
    float*   Kpp     = (float*)alloc((size_t)BSZ * NH * 1024 * 40 * 4);
    float*   Vpp     = (float*)alloc((size_t)BSZ * NH * 1024 * 40 * 4);
    ushortt* rkb     = (ushortt*)alloc((size_t)NH * RLEN * 40 * 2);
    ushortt* vec_bf  = (ushortt*)alloc((size_t)4096 * 384 * 2);
    ushortt* out1_bf = (ushortt*)alloc((size_t)4096 * 384 * 2);
    ushortt* h1_bf   = (ushortt*)alloc((size_t)4096 * 928 * 2);
    float*   attnf   = (float*)alloc((size_t)4096 * DM * 4);
    float*   out1f   = (float*)alloc((size_t)4096 * DM * 4);
    float*   core    = (float*)alloc((size_t)4096 * DM * 4);

    // split-K partials alias the (not-yet-used) attnf/out1f/core region:
    // op: KS*40*1024*40 f32 = 13.11 MB, ml: KS*40*1024 float2 = 0.66 MB  (<= 18.67 MB)
    float*  op_part = attnf;
    float2* ml_part = (float2*)(attnf + (size_t)KS * BSZ * NH * 1024 * 40);

    auto cgrid = [](size_t total) { return dim3((unsigned)((total + 255) / 256)); };
    convpad<<<cgrid((size_t)4096 * 384), 256, 0, stream>>>(w, w_bf, 4096, DM, 4096, 384);
    convpad<<<cgrid((size_t)1152 * 384), 256, 0, stream>>>(qkv_w, qkv_bf, H3, DM, 1152, 384);
    convpad<<<cgrid((size_t)2176 * 384), 256, 0, stream>>>(r, r_bf, RLEN, DM, 2176, 384);
    convpad<<<cgrid((size_t)384 * 384), 256, 0, stream>>>(r_w, rw_bf, DM, DM, 384, 384);
    convpad<<<cgrid((size_t)384 * 384), 256, 0, stream>>>(o_w, ow_bf, DM, DM, 384, 384);
    convpad<<<cgrid((size_t)960 * 384), 256, 0, stream>>>(ffw1, f1_bf, DI, DM, 960, 384);
    convpad<<<cgrid((size_t)384 * 928), 256, 0, stream>>>(ffw2, f2_bf, DM, DI, 384, 928);
    init_pads<<<cgrid((size_t)BSZ * NH * 1024 * 2), 256, 0, stream>>>(qwp, qrp, Kpp, Vpp, rkb, vec_bf);

    // QKV GEMM with scatter epilogue -> qwp/qrp/Kpp/Vpp
    gemm_mfma<5><<<dim3(18, 32), 256, 0, stream>>>(w_bf, qkv_bf, rwb, qwp, 4096, H3, 384, 0,
                                                   rrb, qrp, Kpp, Vpp);
    // rk GEMM -> rkb (bf16, padded per-head rows)
    gemm_mfma<6><<<dim3(6, 17), 256, 0, stream>>>(r_bf, rw_bf, nullptr, rkb, RLEN, DM, 384, 0,
                                                  nullptr, nullptr, nullptr, nullptr);
    // attention: split-K partials, then combine
    attn3<<<dim3(32, BSZ, NH * KS), 256, 0, stream>>>(qwp, qrp, Kpp, Vpp, rkb, relpos,
                                                      op_part, ml_part);
    attn_combine<<<cgrid((size_t)BSZ * NH * 1024 * 38), 256, 0, stream>>>(op_part, ml_part, vec_bf);
    // attn_out = vec @ o_w^T   (overwrites the op_part alias -- partials are dead)
    gemm_mfma<0><<<dim3(6, 32), 256, 0, stream>>>(vec_bf, ow_bf, nullptr, attnf, 4096, DM, 384, DM,
                                                  nullptr, nullptr, nullptr, nullptr);
    ln_kernel<true><<<4096, 256, 0, stream>>>(w, attnf, ln1g, ln1b, out1f, out1_bf);
    gemm_mfma<3><<<dim3(15, 32), 256, 0, stream>>>(out1_bf, f1_bf, ffb1, h1_bf, 4096, DI, 384, 928,
                                                   nullptr, nullptr, nullptr, nullptr);
    gemm_mfma<4><<<dim3(6, 32), 256, 0, stream>>>(h1_bf, f2_bf, ffb2, core, 4096, DM, 928, DM,
                                                  nullptr, nullptr, nullptr, nullptr);
    ln_kernel<false><<<4096, 256, 0, stream>>>(out1f, core, ln2g, ln2b, out, nullptr);
}

// Round 8
// 525.304 us; speedup vs baseline: 2.1857x; 1.0169x over previous
//
#include <hip/hip_runtime.h>
#include <math.h>

#define QLEN 1024
#define BSZ 4
#define NH 10
#define DH 38
#define DM 380
#define DI 900
#define H3 1140
#define RLEN 2049
#define RLP 2112                      // RLEN padded to 33*64
#define SCALE 0.16222142113076254f   // 1/sqrt(38)
#define KS 2                          // k-splits in attention

typedef unsigned short ushortt;
typedef __attribute__((ext_vector_type(8))) short short8;
typedef __attribute__((ext_vector_type(4))) float float4v;

__device__ __forceinline__ float bf2f(ushortt u) {
    return __uint_as_float(((unsigned int)u) << 16);
}
__device__ __forceinline__ ushortt f2bf(float f) {
    unsigned int u = __float_as_uint(f);
    u += 0x7fffu + ((u >> 16) & 1u);   // RNE
    return (ushortt)(u >> 16);
}

// ---------- f32 [R][C] -> bf16 [Rp][Cp], zero-padded ----------
__global__ __launch_bounds__(256)
void convpad(const float* __restrict__ src, ushortt* __restrict__ dst,
             int R, int C, int Rp, int Cp) {
    const int total = Rp * Cp;
    for (int i = blockIdx.x * 256 + threadIdx.x; i < total; i += gridDim.x * 256) {
        int r = i / Cp, c = i - r * Cp;
        float v = (r < R && c < C) ? src[(size_t)r * C + c] : 0.f;
        dst[i] = f2bf(v);
    }
}

// ---------- zero the pad lanes once per launch ----------
__global__ __launch_bounds__(256)
void init_pads(float* __restrict__ qwp, float* __restrict__ Kp, float* __restrict__ Vp,
               ushortt* __restrict__ vec) {
    const int i = blockIdx.x * 256 + threadIdx.x;
    if (i < BSZ * NH * 1024 * 2) {                       // d=38,39 of the head arrays
        size_t idx = (size_t)(i >> 1) * 40 + 38 + (i & 1);
        qwp[idx] = 0.f; Kp[idx] = 0.f; Vp[idx] = 0.f;
    }
    if (i < 4096 * 4) {                                  // vec cols 380..383
        vec[(size_t)(i >> 2) * 384 + 380 + (i & 3)] = 0;
    }
}

// ---------------- bf16 MFMA GEMM:  C[M,N] = A[M,Kp] * B[N,Kp]^T ----------------
// EPI: 0 = f32 store, 3 = relu(x+bias)->bf16 (ld 928), 4 = x+bias->f32,
//      5 = QKV scatter (qwp f32 + qr_bf bf16[64] + Kp/Vp f32),
//      6 = rk -> rk_bf bf16 [n][2112][64], 7 = BD batched GEMM -> BD[b][q][n][2049] bf16
template<int EPI>
__global__ __launch_bounds__(256)
void gemm_mfma(const ushortt* __restrict__ A, const ushortt* __restrict__ B,
               const float* __restrict__ bias, void* __restrict__ Cout,
               int M, int N, int Kpp, int ldc,
               const float* __restrict__ bias2, float* __restrict__ out2,
               float* __restrict__ out3, float* __restrict__ out4, int bofs) {
    __shared__ __align__(16) ushortt As[128 * 32];
    __shared__ __align__(16) ushortt Bs[64 * 32];
    const int tid = threadIdx.x;
    const int wid = tid >> 6, lane = tid & 63;
    const int bRow = blockIdx.y * 128, bCol = blockIdx.x * 64;

    int lb = 0, nh7 = 0;
    if (EPI == 7) {                       // batched: z = local_b * NH + n
        const int z = blockIdx.z;
        lb = z / NH; nh7 = z - lb * NH;
        A += (((size_t)(bofs + lb) * NH + nh7) * 1024) * 64;
        B += (size_t)nh7 * RLP * 64;
    }

    float4v acc[2][4];
    const float4v zz = {0.f, 0.f, 0.f, 0.f};
    #pragma unroll
    for (int m = 0; m < 2; ++m)
        #pragma unroll
        for (int n = 0; n < 4; ++n) acc[m][n] = zz;

    const int arow = tid >> 1, acol = (tid & 1) * 16;
    const int brow = tid >> 2, bcol = (tid & 3) * 8;
    const int fr = lane & 15, kg = lane >> 4;

    for (int k0 = 0; k0 < Kpp; k0 += 32) {
        const ushortt* ag = A + (size_t)(bRow + arow) * Kpp + k0 + acol;
        float4v a0 = *(const float4v*)ag;
        float4v a1 = *(const float4v*)(ag + 8);
        const ushortt* bg = B + (size_t)(bCol + brow) * Kpp + k0 + bcol;
        float4v b0 = *(const float4v*)bg;
        __syncthreads();
        *(float4v*)&As[arow * 32 + acol] = a0;
        *(float4v*)&As[arow * 32 + acol + 8] = a1;
        *(float4v*)&Bs[brow * 32 + bcol] = b0;
        __syncthreads();

        short8 bf[4];
        #pragma unroll
        for (int n = 0; n < 4; ++n)
            bf[n] = *(const short8*)&Bs[(n * 16 + fr) * 32 + kg * 8];
        #pragma unroll
        for (int m = 0; m < 2; ++m) {
            short8 af = *(const short8*)&As[(wid * 32 + m * 16 + fr) * 32 + kg * 8];
            #pragma unroll
            for (int n = 0; n < 4; ++n)
                acc[m][n] = __builtin_amdgcn_mfma_f32_16x16x32_bf16(af, bf[n], acc[m][n], 0, 0, 0);
        }
    }

    #pragma unroll
    for (int m = 0; m < 2; ++m)
        #pragma unroll
        for (int n = 0; n < 4; ++n)
            #pragma unroll
            for (int j = 0; j < 4; ++j) {
                const int row = bRow + wid * 32 + m * 16 + (lane >> 4) * 4 + j;
                const int col = bCol + n * 16 + (lane & 15);
                const float v = acc[m][n][j];
                if (EPI == 0) {
                    if (row < M && col < N) ((float*)Cout)[(size_t)row * ldc + col] = v;
                } else if (EPI == 3) {
                    if (row < M && col < 928) {
                        float h = (col < DI) ? fmaxf(v + bias[col], 0.f) : 0.f;
                        ((ushortt*)Cout)[(size_t)row * 928 + col] = f2bf(h);
                    }
                } else if (EPI == 4) {
                    if (row < M && col < N) ((float*)Cout)[(size_t)row * ldc + col] = v + bias[col];
                } else if (EPI == 5) {
                    if (col < H3) {
                        int part = col / 380;
                        int c = col - part * 380;
                        int nh = c / 38, d = c - nh * 38;
                        int q = row >> 2, b2 = row & 3;
                        size_t idx = (((size_t)b2 * NH + nh) * 1024 + q) * 40 + d;
                        if (part == 0) {
                            ((float*)Cout)[idx] = v + bias[c];                 // qwp (+r_w_bias)
                            ((ushortt*)out2)[(((size_t)b2 * NH + nh) * 1024 + q) * 64 + d]
                                = f2bf(v + bias2[c]);                          // qr_bf (+r_r_bias)
                        } else if (part == 1) out3[idx] = v;                   // Kp
                        else out4[idx] = v;                                    // Vp
                    }
                } else if (EPI == 6) {
                    if (row < RLEN && col < DM) {
                        int nh = col / 38, d = col - nh * 38;
                        ((ushortt*)Cout)[((size_t)nh * RLP + row) * 64 + d] = f2bf(v);
                    }
                } else {  // EPI 7: BD store, coalesced along j
                    if (col < RLEN)
                        ((ushortt*)Cout)[(((size_t)lb * 1024 + row) * NH + nh7) * RLEN + col] = f2bf(v);
                }
            }
}

// ---------------- split-K fused attention, 32 q-rows per block ----------------
// qwp/Kp/Vp: f32 [b][n][1024][40]; BD: bf16 [lb][1024][NH][2049]
__global__ __launch_bounds__(256)
void attn4(const float* __restrict__ qwp, const float* __restrict__ Kp,
           const float* __restrict__ Vp, const ushortt* __restrict__ BD,
           const int* __restrict__ relpos,
           float* __restrict__ op, float2* __restrict__ ml, int b0) {
    const int qc = 31 - blockIdx.x;              // heavy chunks dispatch first
    const int qbase = qc * 32;
    const int b = b0 + blockIdx.y;
    const int n = blockIdx.z % NH, s = blockIdx.z / NH;
    const int tid = threadIdx.x;
    const int row = tid >> 3, kg = tid & 7;
    const int qi = qbase + row;
    const size_t bn = (size_t)b * NH + n;
    const size_t prow = ((size_t)s * (BSZ * NH) + bn) * 1024 + qi;

    const int ntchunk = (qbase + 95) >> 6;       // ceil((qbase+32)/64)
    const int tbeg = s * 8;                      // KS=2: 8 tiles (=512 k) per split
    const int tend = min(tbeg + 8, ntchunk);
    if (tbeg >= tend) {                          // inactive split
        if (kg == 0) ml[prow] = make_float2(-INFINITY, 0.f);
        return;
    }

    __shared__ __align__(16) float KtL[64 * 40];
    __shared__ __align__(16) float VtL[64 * 40];
    __shared__ float pL[32 * 66];

    const float* Kbase = Kp + bn * 1024 * 40;
    const float* Vbase = Vp + bn * 1024 * 40;

    // preload own qw row into registers
    float4v qw[10];
    {
        const float4v* src = (const float4v*)(qwp + (bn * 1024 + qi) * 40);
        #pragma unroll
        for (int i = 0; i < 10; ++i) qw[i] = src[i];
    }
    float o[5] = {0.f, 0.f, 0.f, 0.f, 0.f};
    float mrun = -INFINITY, lrun = 0.f;
    const int* rp = relpos + ((size_t)b * QLEN + qi) * QLEN;
    const ushortt* bdrow = BD + (((size_t)blockIdx.y * 1024 + qi) * NH + n) * RLEN;

    for (int kt = tbeg; kt < tend; ++kt) {
        const int k0 = kt * 64;
        __syncthreads();
        {
            const float4v* ks = (const float4v*)(Kbase + (size_t)k0 * 40);
            const float4v* vs = (const float4v*)(Vbase + (size_t)k0 * 40);
            for (int e = tid; e < 640; e += 256) {
                ((float4v*)KtL)[e] = ks[e];
                ((float4v*)VtL)[e] = vs[e];
            }
        }
        __syncthreads();

        // prefetch relpos -> j indices, then BD values (breaks the serial chain)
        int jv[8];
        #pragma unroll
        for (int ss = 0; ss < 8; ++ss) {
            const int kk = k0 + kg + ss * 8;
            int j = -1;
            if (kk <= qi) {
                int rpv = rp[kk];
                rpv = rpv < -1024 ? -1024 : (rpv > 1024 ? 1024 : rpv);
                j = 1024 - rpv;
            }
            jv[ss] = j;
        }
        float bdv[8];
        #pragma unroll
        for (int ss = 0; ss < 8; ++ss)
            bdv[ss] = (jv[ss] >= 0) ? bf2f(bdrow[jv[ss]]) : 0.f;

        float sarr[8];
        float pmax = -INFINITY;
        #pragma unroll
        for (int ss = 0; ss < 8; ++ss) {
            float sv = -INFINITY;
            if (jv[ss] >= 0) {
                const int k = kg + ss * 8;
                float acc1 = 0.f;
                const float4v* kt4 = (const float4v*)(KtL + k * 40);
                #pragma unroll
                for (int i = 0; i < 10; ++i) {
                    float4v kv = kt4[i];
                    acc1 += qw[i][0] * kv[0] + qw[i][1] * kv[1]
                          + qw[i][2] * kv[2] + qw[i][3] * kv[3];
                }
                sv = (acc1 + bdv[ss]) * SCALE;
            }
            sarr[ss] = sv;
            pmax = fmaxf(pmax, sv);
        }
        pmax = fmaxf(pmax, __shfl_xor(pmax, 1, 64));
        pmax = fmaxf(pmax, __shfl_xor(pmax, 2, 64));
        pmax = fmaxf(pmax, __shfl_xor(pmax, 4, 64));
        const float nm = fmaxf(mrun, pmax);
        const float corr = __expf(mrun - nm);   // first tile: exp(-inf)=0
        float psum = 0.f;
        float* prw = pL + row * 66;
        #pragma unroll
        for (int ss = 0; ss < 8; ++ss) {
            float p = __expf(sarr[ss] - nm);
            psum += p;
            prw[kg + ss * 8] = p;
        }
        psum += __shfl_xor(psum, 1, 64);
        psum += __shfl_xor(psum, 2, 64);
        psum += __shfl_xor(psum, 4, 64);
        lrun = lrun * corr + psum;
        mrun = nm;
        #pragma unroll
        for (int jj = 0; jj < 5; ++jj) o[jj] *= corr;
        int kmax = qi - k0 + 1; if (kmax > 64) kmax = 64;
        #pragma unroll 4
        for (int k = 0; k < kmax; ++k) {
            float p = prw[k];
            const float* vr = VtL + k * 40;
            float4v v4 = *(const float4v*)(vr + 4 * kg);
            float v1 = vr[32 + kg];
            o[0] += p * v4[0]; o[1] += p * v4[1];
            o[2] += p * v4[2]; o[3] += p * v4[3];
            o[4] += p * v1;
        }
    }
    float* oprow = op + prow * 40;
    #pragma unroll
    for (int jj = 0; jj < 4; ++jj) oprow[4 * kg + jj] = o[jj];
    oprow[32 + kg] = o[4];
    if (kg == 0) ml[prow] = make_float2(mrun, lrun);
}

// ---------------- combine split-K partials -> vec (bf16) ----------------
__global__ __launch_bounds__(256)
void attn_combine(const float* __restrict__ op, const float2* __restrict__ ml,
                  ushortt* __restrict__ vec) {
    const int idx = blockIdx.x * 256 + threadIdx.x;
    if (idx >= BSZ * NH * 1024 * 38) return;
    const int d = idx % 38;
    const int rh = idx / 38;                 // bn*1024 + q
    const int q = rh & 1023;
    const int bn = rh >> 10;
    const int b = bn / NH, n = bn - b * NH;
    const float2 a = ml[rh];
    const float2 c = ml[(size_t)BSZ * NH * 1024 + rh];
    const float M = fmaxf(a.x, c.x);
    float l = 0.f, o = 0.f;
    if (a.y > 0.f) {
        float w = __expf(a.x - M);
        l += a.y * w;
        o += op[(size_t)rh * 40 + d] * w;
    }
    if (c.y > 0.f) {
        float w = __expf(c.x - M);
        l += c.y * w;
        o += op[((size_t)BSZ * NH * 1024 + rh) * 40 + d] * w;
    }
    vec[((size_t)q * BSZ + b) * 384 + (size_t)n * 38 + d] = f2bf(o / l);
}

// ---------------- residual + LayerNorm ----------------
template<bool WRITE_BF>
__global__ __launch_bounds__(256)
void ln_kernel(const float* __restrict__ x1, const float* __restrict__ x2,
               const float* __restrict__ g, const float* __restrict__ bb,
               float* __restrict__ outf, ushortt* __restrict__ outbf) {
    const int row = blockIdx.x;
    const float* p1 = x1 + (size_t)row * DM;
    const float* p2 = x2 + (size_t)row * DM;
    __shared__ float xb[DM];
    __shared__ float red[256];
    const int tid = threadIdx.x;
    float s = 0.f;
    for (int i = tid; i < DM; i += 256) { float v = p1[i] + p2[i]; xb[i] = v; s += v; }
    red[tid] = s; __syncthreads();
    for (int st = 128; st > 0; st >>= 1) { if (tid < st) red[tid] += red[tid + st]; __syncthreads(); }
    const float mean = red[0] / DM;
    __syncthreads();
    float s2 = 0.f;
    for (int i = tid; i < DM; i += 256) { float d = xb[i] - mean; s2 += d * d; }
    red[tid] = s2; __syncthreads();
    for (int st = 128; st > 0; st >>= 1) { if (tid < st) red[tid] += red[tid + st]; __syncthreads(); }
    const float rstd = rsqrtf(red[0] / DM + 1e-5f);
    for (int i = tid; i < (WRITE_BF ? 384 : DM); i += 256) {
        float v = 0.f;
        if (i < DM) {
            v = (xb[i] - mean) * rstd * g[i] + bb[i];
            outf[(size_t)row * DM + i] = v;
        }
        if (WRITE_BF) outbf[(size_t)row * 384 + i] = f2bf(i < DM ? v : 0.f);
    }
}

extern "C" void kernel_launch(void* const* d_in, const int* in_sizes, int n_in,
                              void* d_out, int out_size, void* d_ws, size_t ws_size,
                              hipStream_t stream) {
    const float* w     = (const float*)d_in[0];
    const float* r     = (const float*)d_in[1];
    const float* rwb   = (const float*)d_in[2];
    const float* rrb   = (const float*)d_in[3];
    const float* qkv_w = (const float*)d_in[4];
    const float* r_w   = (const float*)d_in[5];
    const float* o_w   = (const float*)d_in[6];
    const float* ln1g  = (const float*)d_in[7];
    const float* ln1b  = (const float*)d_in[8];
    const float* ffw1  = (const float*)d_in[9];
    const float* ffb1  = (const float*)d_in[10];
    const float* ffw2  = (const float*)d_in[11];
    const float* ffb2  = (const float*)d_in[12];
    const float* ln2g  = (const float*)d_in[13];
    const float* ln2b  = (const float*)d_in[14];
    const int*   relpos = (const int*)d_in[16];
    float* out = (float*)d_out;

    char* cur = (char*)d_ws;
    auto alloc = [&](size_t bytes) { char* p = cur; cur += (bytes + 255) & ~(size_t)255; return p; };
    ushortt* w_bf    = (ushortt*)alloc((size_t)4096 * 384 * 2);
    ushortt* qkv_bf  = (ushortt*)alloc((size_t)1152 * 384 * 2);
    ushortt* r_bf    = (ushortt*)alloc((size_t)2176 * 384 * 2);
    ushortt* rw_bf   = (ushortt*)alloc((size_t)384 * 384 * 2);
    ushortt* ow_bf   = (ushortt*)alloc((size_t)384 * 384 * 2);
    ushortt* f1_bf   = (ushortt*)alloc((size_t)960 * 384 * 2);
    ushortt* f2_bf   = (ushortt*)alloc((size_t)384 * 928 * 2);
    float*   qwp     = (float*)alloc((size_t)BSZ * NH * 1024 * 40 * 4);
    float*   Kpp     = (float*)alloc((size_t)BSZ * NH * 1024 * 40 * 4);
    float*   Vpp     = (float*)alloc((size_t)BSZ * NH * 1024 * 40 * 4);
    ushortt* qr_bf   = (ushortt*)alloc((size_t)BSZ * NH * 1024 * 64 * 2);
    ushortt* rk_bf   = (ushortt*)alloc((size_t)NH * RLP * 64 * 2);
    ushortt* vec_bf  = (ushortt*)alloc((size_t)4096 * 384 * 2);
    ushortt* out1_bf = (ushortt*)alloc((size_t)4096 * 384 * 2);
    ushortt* h1_bf   = (ushortt*)alloc((size_t)4096 * 928 * 2);
    float*   attnf   = (float*)alloc((size_t)4096 * DM * 4);
    float*   out1f   = (float*)alloc((size_t)4096 * DM * 4);
    float*   core    = (float*)alloc((size_t)4096 * DM * 4);

    // split-K partials alias attnf/out1f/core (dead until after combine)
    float*  op_part = attnf;
    float2* ml_part = (float2*)(attnf + (size_t)KS * BSZ * NH * 1024 * 40);

    // BD buffer: bf16 [lb][1024][NH][2049]
    const size_t bd_b_bytes = (size_t)1024 * NH * RLEN * 2;   // per-b: ~41 MB
    ushortt* BD = (ushortt*)alloc(bd_b_bytes * BSZ);
    bool full = ((size_t)(cur - (char*)d_ws) <= ws_size);
    if (!full) { cur = (char*)BD; BD = (ushortt*)alloc(bd_b_bytes); }  // per-b reuse

    auto cgrid = [](size_t total) { return dim3((unsigned)((total + 255) / 256)); };
    hipMemsetAsync(qr_bf, 0, (size_t)BSZ * NH * 1024 * 64 * 2, stream);
    hipMemsetAsync(rk_bf, 0, (size_t)NH * RLP * 64 * 2, stream);
    convpad<<<cgrid((size_t)4096 * 384), 256, 0, stream>>>(w, w_bf, 4096, DM, 4096, 384);
    convpad<<<cgrid((size_t)1152 * 384), 256, 0, stream>>>(qkv_w, qkv_bf, H3, DM, 1152, 384);
    convpad<<<cgrid((size_t)2176 * 384), 256, 0, stream>>>(r, r_bf, RLEN, DM, 2176, 384);
    convpad<<<cgrid((size_t)384 * 384), 256, 0, stream>>>(r_w, rw_bf, DM, DM, 384, 384);
    convpad<<<cgrid((size_t)384 * 384), 256, 0, stream>>>(o_w, ow_bf, DM, DM, 384, 384);
    convpad<<<cgrid((size_t)960 * 384), 256, 0, stream>>>(ffw1, f1_bf, DI, DM, 960, 384);
    convpad<<<cgrid((size_t)384 * 928), 256, 0, stream>>>(ffw2, f2_bf, DM, DI, 384, 928);
    init_pads<<<cgrid((size_t)BSZ * NH * 1024 * 2), 256, 0, stream>>>(qwp, Kpp, Vpp, vec_bf);

    // QKV GEMM with scatter epilogue -> qwp / qr_bf / Kpp / Vpp
    gemm_mfma<5><<<dim3(18, 32), 256, 0, stream>>>(w_bf, qkv_bf, rwb, qwp, 4096, H3, 384, 0,
                                                   rrb, (float*)qr_bf, Kpp, Vpp, 0);
    // rk GEMM -> rk_bf  bf16 [n][2112][64]
    gemm_mfma<6><<<dim3(6, 17), 256, 0, stream>>>(r_bf, rw_bf, nullptr, rk_bf, RLEN, DM, 384, 0,
                                                  nullptr, nullptr, nullptr, nullptr, 0);
    if (full) {
        // BDfull = qr @ rk^T, batched over all (b,n)
        gemm_mfma<7><<<dim3(33, 8, BSZ * NH), 256, 0, stream>>>(
            qr_bf, rk_bf, nullptr, BD, 1024, RLEN, 64, 0,
            nullptr, nullptr, nullptr, nullptr, 0);
        attn4<<<dim3(32, BSZ, NH * KS), 256, 0, stream>>>(qwp, Kpp, Vpp, BD, relpos,
                                                          op_part, ml_part, 0);
    } else {
        for (int b = 0; b < BSZ; ++b) {
            gemm_mfma<7><<<dim3(33, 8, NH), 256, 0, stream>>>(
                qr_bf, rk_bf, nullptr, BD, 1024, RLEN, 64, 0,
                nullptr, nullptr, nullptr, nullptr, b);
            attn4<<<dim3(32, 1, NH * KS), 256, 0, stream>>>(qwp, Kpp, Vpp, BD, relpos,
                                                            op_part, ml_part, b);
        }
    }
    attn_combine<<<cgrid((size_t)BSZ * NH * 1024 * 38), 256, 0, stream>>>(op_part, ml_part, vec_bf);
    // attn_out = vec @ o_w^T   (overwrites op_part alias -- partials are dead)
    gemm_mfma<0><<<dim3(6, 32), 256, 0, stream>>>(vec_bf, ow_bf, nullptr, attnf, 4096, DM, 384, DM,
                                                  nullptr, nullptr, nullptr, nullptr, 0);
    ln_kernel<true><<<4096, 256, 0, stream>>>(w, attnf, ln1g, ln1b, out1f, out1_bf);
    gemm_mfma<3><<<dim3(15, 32), 256, 0, stream>>>(out1_bf, f1_bf, ffb1, h1_bf, 4096, DI, 384, 928,
                                                   nullptr, nullptr, nullptr, nullptr, 0);
    gemm_mfma<4><<<dim3(6, 32), 256, 0, stream>>>(h1_bf, f2_bf, ffb2, core, 4096, DM, 928, DM,
                                                  nullptr, nullptr, nullptr, nullptr, 0);
    ln_kernel<false><<<4096, 256, 0, stream>>>(out1f, core, ln2g, ln2b, out, nullptr);
}